// Round 9
// baseline (136.484 us; speedup 1.0000x reference)
//
#include <hip/hip_runtime.h>

#define EPS 1e-6f

constexpr int C    = 128;
constexpr int HW   = 65536;    // 256*256
constexpr int TILE = 256;      // pixels per block -> 1 KB per channel per block
constexpr int NT   = 1024;     // 16 waves

typedef __attribute__((ext_vector_type(8))) short bf16x8;
typedef __attribute__((ext_vector_type(4))) float f32x4;

__device__ __forceinline__ unsigned short f2bf(float f) {   // RNE
    unsigned u = __float_as_uint(f);
    u += 0x7fff + ((u >> 16) & 1);
    return (unsigned short)(u >> 16);
}
__device__ __forceinline__ float bf2f(unsigned short u) {
    return __uint_as_float(((unsigned)u) << 16);
}
__device__ __forceinline__ unsigned pack2(float lo, float hi) {
    return (unsigned)f2bf(lo) | ((unsigned)f2bf(hi) << 16);
}

__global__ __launch_bounds__(NT, 2) void spnorm_kernel(
    const float* __restrict__ x, const float* __restrict__ W,
    const float* __restrict__ bias, float* __restrict__ out)
{
    // bufT[p][c]: normalized bf16, transposed, XOR-swizzled (byte ^= (p&15)<<4)
    __shared__ unsigned short bufT[TILE * C];              // 64 KB
    __shared__ float4 red[8][128];                         // 16 KB {s1e,s2e,s1o,s2o}
    __shared__ float u_s[TILE], se_s[TILE];                // 2 KB

    const int tid = threadIdx.x;
    const int l   = tid & 63;
    const int wv  = tid >> 6;                              // 0..15
    const int batch = blockIdx.x >> 8;                     // 256 blocks per image
    const int hw0   = (blockIdx.x & 255) * TILE;
    const int base  = batch * (C * HW) + hw0;

    const int p2 = tid & 127;                              // pixel-pair id (px 2*p2, 2*p2+1)
    const int q  = tid >> 7;                               // channel group (16 ch), 0..7

    // ---- Phase 1: float2 loads (512 B/wave-inst), stats from fp32, pack to bf16 pairs.
    //      Per-thread state: 16 packed regs (no spill, no remat at the 64-reg cap). ----
    unsigned vp[16];
    float s1e = 0.f, s2e = 0.f, s1o = 0.f, s2o = 0.f;
    {
        const float* xp = x + base + q * 16 * HW + 2 * p2;
        #pragma unroll
        for (int i = 0; i < 16; ++i) {
            float2 t = *reinterpret_cast<const float2*>(xp + i * HW);
            s1e += t.x; s2e = fmaf(t.x, t.x, s2e);
            s1o += t.y; s2o = fmaf(t.y, t.y, s2o);
            vp[i] = pack2(t.x, t.y);
        }
    }

    // ---- Phase 2: partial sums -> LDS ----
    red[q][p2] = make_float4(s1e, s2e, s1o, s2o);
    __syncthreads();

    // ---- Phase 3: finalize both pixels, normalize packed regs, write bufT ----
    {
        float s1a = 0.f, s2a = 0.f, s1b = 0.f, s2b = 0.f;
        #pragma unroll
        for (int j = 0; j < 8; ++j) {
            float4 r = red[j][p2];
            s1a += r.x; s2a += r.y;
            s1b += r.z; s2b += r.w;
        }
        float u0   = s1a * (1.0f / 128.0f);
        float var0 = fmaxf((s2a - s1a * u0) * (1.0f / 127.0f), 0.0f);
        float se0  = sqrtf(var0) + EPS;
        float iv0  = 1.0f / se0;
        float u1   = s1b * (1.0f / 128.0f);
        float var1 = fmaxf((s2b - s1b * u1) * (1.0f / 127.0f), 0.0f);
        float se1  = sqrtf(var1) + EPS;
        float iv1  = 1.0f / se1;
        if (q == 0) {                          // wave-uniform (waves 0,1)
            u_s[2 * p2]      = u0;
            se_s[2 * p2]     = se0;
            u_s[2 * p2 + 1]  = u1;
            se_s[2 * p2 + 1] = se1;
        }

        char* tb = (char*)bufT;
        const int row0 = 2 * p2;
        // even pixel (lo halves)
        {
            const int rowoff = row0 * 256;
            const int swz    = (row0 & 15) << 4;
            #pragma unroll
            for (int h = 0; h < 2; ++h) {
                float n0 = (bf2f((unsigned short)(vp[h*8+0] & 0xffffu)) - u0) * iv0;
                float n1 = (bf2f((unsigned short)(vp[h*8+1] & 0xffffu)) - u0) * iv0;
                float n2 = (bf2f((unsigned short)(vp[h*8+2] & 0xffffu)) - u0) * iv0;
                float n3 = (bf2f((unsigned short)(vp[h*8+3] & 0xffffu)) - u0) * iv0;
                float n4 = (bf2f((unsigned short)(vp[h*8+4] & 0xffffu)) - u0) * iv0;
                float n5 = (bf2f((unsigned short)(vp[h*8+5] & 0xffffu)) - u0) * iv0;
                float n6 = (bf2f((unsigned short)(vp[h*8+6] & 0xffffu)) - u0) * iv0;
                float n7 = (bf2f((unsigned short)(vp[h*8+7] & 0xffffu)) - u0) * iv0;
                uint4 d;
                d.x = pack2(n0, n1);
                d.y = pack2(n2, n3);
                d.z = pack2(n4, n5);
                d.w = pack2(n6, n7);
                int byte = (rowoff + (q * 2 + h) * 16) ^ swz;
                *reinterpret_cast<uint4*>(tb + byte) = d;
            }
        }
        // odd pixel (hi halves)
        {
            const int rowoff = (row0 + 1) * 256;
            const int swz    = ((row0 + 1) & 15) << 4;
            #pragma unroll
            for (int h = 0; h < 2; ++h) {
                float n0 = (bf2f((unsigned short)(vp[h*8+0] >> 16)) - u1) * iv1;
                float n1 = (bf2f((unsigned short)(vp[h*8+1] >> 16)) - u1) * iv1;
                float n2 = (bf2f((unsigned short)(vp[h*8+2] >> 16)) - u1) * iv1;
                float n3 = (bf2f((unsigned short)(vp[h*8+3] >> 16)) - u1) * iv1;
                float n4 = (bf2f((unsigned short)(vp[h*8+4] >> 16)) - u1) * iv1;
                float n5 = (bf2f((unsigned short)(vp[h*8+5] >> 16)) - u1) * iv1;
                float n6 = (bf2f((unsigned short)(vp[h*8+6] >> 16)) - u1) * iv1;
                float n7 = (bf2f((unsigned short)(vp[h*8+7] >> 16)) - u1) * iv1;
                uint4 d;
                d.x = pack2(n0, n1);
                d.y = pack2(n2, n3);
                d.z = pack2(n4, n5);
                d.w = pack2(n6, n7);
                int byte = (rowoff + (q * 2 + h) * 16) ^ swz;
                *reinterpret_cast<uint4*>(tb + byte) = d;
            }
        }
    }

    // ---- A-fragments: W (fp32 -> bf16); loaded after vp[] is dead.
    //      Wave wv -> o-tile wm = wv&7, px-half wn = wv>>3. ----
    const int wm = wv & 7;
    const int wn = wv >> 3;
    const int arow  = (wm << 4) + (l & 15);
    const int acol0 = (l >> 4) << 3;
    bf16x8 afrag[4];
    #pragma unroll
    for (int kk = 0; kk < 4; ++kk) {
        const float* wp = W + arow * C + kk * 32 + acol0;
        float4 wa = *reinterpret_cast<const float4*>(wp);
        float4 wb = *reinterpret_cast<const float4*>(wp + 4);
        bf16x8 f;
        f[0] = (short)f2bf(wa.x); f[1] = (short)f2bf(wa.y);
        f[2] = (short)f2bf(wa.z); f[3] = (short)f2bf(wa.w);
        f[4] = (short)f2bf(wb.x); f[5] = (short)f2bf(wb.y);
        f[6] = (short)f2bf(wb.z); f[7] = (short)f2bf(wb.w);
        afrag[kk] = f;
    }
    const int od = (wm << 4) + ((l >> 4) << 2);
    const f32x4 binit = { bias[od], bias[od + 1], bias[od + 2], bias[od + 3] };
    __syncthreads();

    // ---- Phase 4: MFMA conv + epilogue. Wave: 16 o x 128 px (its px-half).
    //      Block writes 1 KB contiguous per channel. ----
    {
        const char* tb = (const char*)bufT;
        const int pcol = l & 15;
        const int koff = (l >> 4) << 4;
        const int swz  = pcol << 4;
        float* outp = out + base;
        #pragma unroll
        for (int pt = 0; pt < 8; ++pt) {
            const int pp     = (wn << 7) + (pt << 4) + pcol;
            const int rowoff = pp * 256;
            f32x4 acc = binit;
            #pragma unroll
            for (int kk = 0; kk < 4; ++kk) {
                int byte = (rowoff + kk * 64 + koff) ^ swz;
                bf16x8 bfrag = *reinterpret_cast<const bf16x8*>(tb + byte);
                acc = __builtin_amdgcn_mfma_f32_16x16x32_bf16(afrag[kk], bfrag, acc, 0, 0, 0);
            }
            const float uu = u_s[pp];
            const float se = se_s[pp];
            int nbyte = (rowoff + od * 2) ^ swz;
            uint2 nn = *reinterpret_cast<const uint2*>(tb + nbyte);
            float x0 = fmaf(bf2f((unsigned short)(nn.x & 0xffffu)), se, uu);
            float x1 = fmaf(bf2f((unsigned short)(nn.x >> 16)),     se, uu);
            float x2 = fmaf(bf2f((unsigned short)(nn.y & 0xffffu)), se, uu);
            float x3 = fmaf(bf2f((unsigned short)(nn.y >> 16)),     se, uu);
            outp[(od + 0) * HW + pp] = x0 * acc[0];
            outp[(od + 1) * HW + pp] = x1 * acc[1];
            outp[(od + 2) * HW + pp] = x2 * acc[2];
            outp[(od + 3) * HW + pp] = x3 * acc[3];
        }
    }
}

extern "C" void kernel_launch(void* const* d_in, const int* in_sizes, int n_in,
                              void* d_out, int out_size, void* d_ws, size_t ws_size,
                              hipStream_t stream) {
    const float* x = (const float*)d_in[0];
    const float* W = (const float*)d_in[1];
    const float* b = (const float*)d_in[2];
    float* out     = (float*)d_out;

    const int nblk = 8 * HW / TILE;            // 2048 blocks
    spnorm_kernel<<<nblk, NT, 0, stream>>>(x, W, b, out);
}

// Round 10
// 133.900 us; speedup vs baseline: 1.0193x; 1.0193x over previous
//
#include <hip/hip_runtime.h>

#define EPS 1e-6f

constexpr int C    = 128;
constexpr int HW   = 65536;    // 256*256
constexpr int TILE = 128;      // pixels per block (512 B per channel per block)
constexpr int NT   = 512;      // 8 waves

typedef __attribute__((ext_vector_type(8))) short bf16x8;
typedef __attribute__((ext_vector_type(4))) float f32x4;

__device__ __forceinline__ unsigned short f2bf(float f) {   // RNE
    unsigned u = __float_as_uint(f);
    u += 0x7fff + ((u >> 16) & 1);
    return (unsigned short)(u >> 16);
}
__device__ __forceinline__ float bf2f(unsigned short u) {
    return __uint_as_float(((unsigned)u) << 16);
}
__device__ __forceinline__ unsigned pack2(float lo, float hi) {
    return (unsigned)f2bf(lo) | ((unsigned)f2bf(hi) << 16);
}

__global__ __launch_bounds__(NT, 4) void spnorm_kernel(
    const float* __restrict__ x, const float* __restrict__ W,
    const float* __restrict__ bias, float* __restrict__ out)
{
    // bufT[p][c]: normalized bf16, transposed, XOR-swizzled (byte ^= (p&15)<<4)
    __shared__ unsigned short bufT[TILE * C];              // 32 KB
    __shared__ float u_s[TILE], se_s[TILE];                // 1 KB

    const int tid = threadIdx.x;
    const int l   = tid & 63;
    const int wv  = tid >> 6;                              // 0..7
    const int batch = blockIdx.x >> 9;                     // 512 blocks per image
    const int hw0   = (blockIdx.x & 511) * TILE;
    const int base  = batch * (C * HW) + hw0;

    // wave-autonomous stats map: wave wv owns pixels wv*16..wv*16+15.
    // lane = (g, p16): channel group g = l>>4 (32 ch), pixel p16 = l&15.
    const int g   = l >> 4;
    const int p16 = l & 15;
    const int pix = (wv << 4) + p16;                       // 0..127

    // ---- Phase 1: x straight into registers (32 channels of this lane's pixel) ----
    float v[32];
    {
        const float* xp = x + base + g * 32 * HW + pix;
        #pragma unroll
        for (int i = 0; i < 32; ++i)
            v[i] = xp[i * HW];
    }

    // ---- Phase 2: in-wave stats. Partials for a pixel sit in lanes g=0..3 of the
    //      same wave -> butterfly over lane-xor {16,32}; every lane ends with sums. ----
    float u, se, iv;
    {
        float s1 = 0.f, s2 = 0.f;
        #pragma unroll
        for (int i = 0; i < 32; ++i) {
            s1 += v[i];
            s2 = fmaf(v[i], v[i], s2);
        }
        s1 += __shfl_xor(s1, 16);
        s2 += __shfl_xor(s2, 16);
        s1 += __shfl_xor(s1, 32);
        s2 += __shfl_xor(s2, 32);
        u         = s1 * (1.0f / 128.0f);
        float var = fmaxf((s2 - s1 * u) * (1.0f / 127.0f), 0.0f);
        se        = sqrtf(var) + EPS;
        iv        = 1.0f / se;
        if (g == 0) {                       // lanes 0-15 of each wave cover all 128 px
            u_s[pix]  = u;
            se_s[pix] = se;
        }
    }

    // ---- Phase 3: normalize regs, write bufT row=pix, cols g*32..+31 (swizzled).
    //      Bank math: 16 rows x 4 col-groups/instr = 8 dwords/bank = structural min. ----
    {
        char* tb = (char*)bufT;
        const int rowoff = pix * 256;        // 128 ushort per pixel row
        const int swz    = (pix & 15) << 4;
        #pragma unroll
        for (int o8 = 0; o8 < 4; ++o8) {
            float n0 = (v[o8 * 8 + 0] - u) * iv;
            float n1 = (v[o8 * 8 + 1] - u) * iv;
            float n2 = (v[o8 * 8 + 2] - u) * iv;
            float n3 = (v[o8 * 8 + 3] - u) * iv;
            float n4 = (v[o8 * 8 + 4] - u) * iv;
            float n5 = (v[o8 * 8 + 5] - u) * iv;
            float n6 = (v[o8 * 8 + 6] - u) * iv;
            float n7 = (v[o8 * 8 + 7] - u) * iv;
            uint4 d;
            d.x = pack2(n0, n1);
            d.y = pack2(n2, n3);
            d.z = pack2(n4, n5);
            d.w = pack2(n6, n7);
            int byte = (rowoff + (g * 4 + o8) * 16) ^ swz;   // col-octet g*4+o8
            *reinterpret_cast<uint4*>(tb + byte) = d;
        }
    }

    // ---- A-fragments: W (fp32 -> bf16), loaded after v[] is dead ----
    const int arow  = (wv << 4) + (l & 15);
    const int acol0 = (l >> 4) << 3;
    bf16x8 afrag[4];
    #pragma unroll
    for (int kk = 0; kk < 4; ++kk) {
        const float* wp = W + arow * C + kk * 32 + acol0;
        float4 wa = *reinterpret_cast<const float4*>(wp);
        float4 wb = *reinterpret_cast<const float4*>(wp + 4);
        bf16x8 f;
        f[0] = (short)f2bf(wa.x); f[1] = (short)f2bf(wa.y);
        f[2] = (short)f2bf(wa.z); f[3] = (short)f2bf(wa.w);
        f[4] = (short)f2bf(wb.x); f[5] = (short)f2bf(wb.y);
        f[6] = (short)f2bf(wb.z); f[7] = (short)f2bf(wb.w);
        afrag[kk] = f;
    }
    const int od = (wv << 4) + ((l >> 4) << 2);
    const f32x4 binit = { bias[od], bias[od + 1], bias[od + 2], bias[od + 3] };
    __syncthreads();                         // the ONE barrier

    // ---- Phase 4: MFMA conv + epilogue. Wave wv: 16 o x 128 px (8 tiles x 4 K-steps) ----
    {
        const char* tb = (const char*)bufT;
        const int pcol = l & 15;
        const int koff = (l >> 4) << 4;
        const int swz  = pcol << 4;
        float* outp = out + base;
        #pragma unroll
        for (int pt = 0; pt < 8; ++pt) {
            const int pp     = (pt << 4) + pcol;
            const int rowoff = pp * 256;
            f32x4 acc = binit;
            #pragma unroll
            for (int kk = 0; kk < 4; ++kk) {
                int byte = (rowoff + kk * 64 + koff) ^ swz;
                bf16x8 bfrag = *reinterpret_cast<const bf16x8*>(tb + byte);
                acc = __builtin_amdgcn_mfma_f32_16x16x32_bf16(afrag[kk], bfrag, acc, 0, 0, 0);
            }
            const float uu  = u_s[pp];
            const float sep = se_s[pp];
            int nbyte = (rowoff + od * 2) ^ swz;
            uint2 nn = *reinterpret_cast<const uint2*>(tb + nbyte);
            float x0 = fmaf(bf2f((unsigned short)(nn.x & 0xffffu)), sep, uu);
            float x1 = fmaf(bf2f((unsigned short)(nn.x >> 16)),     sep, uu);
            float x2 = fmaf(bf2f((unsigned short)(nn.y & 0xffffu)), sep, uu);
            float x3 = fmaf(bf2f((unsigned short)(nn.y >> 16)),     sep, uu);
            outp[(od + 0) * HW + pp] = x0 * acc[0];
            outp[(od + 1) * HW + pp] = x1 * acc[1];
            outp[(od + 2) * HW + pp] = x2 * acc[2];
            outp[(od + 3) * HW + pp] = x3 * acc[3];
        }
    }
}

extern "C" void kernel_launch(void* const* d_in, const int* in_sizes, int n_in,
                              void* d_out, int out_size, void* d_ws, size_t ws_size,
                              hipStream_t stream) {
    const float* x = (const float*)d_in[0];
    const float* W = (const float*)d_in[1];
    const float* b = (const float*)d_in[2];
    float* out     = (float*)d_out;

    const int nblk = 8 * HW / TILE;            // 4096 blocks
    spnorm_kernel<<<nblk, NT, 0, stream>>>(x, W, b, out);
}